// Round 2
// baseline (837.358 us; speedup 1.0000x reference)
//
#include <hip/hip_runtime.h>
#include <math.h>

// Problem constants
#define B_ 4
#define C_ 256
#define H_ 64
#define W_ 64
#define HW_ 4096
#define CO_ 256
#define KK_ 9
#define NPX_ 16384          // B*H*W
#define GN_EPS_ 1e-5f

// ---------------- K0: transpose weights w[oc][c][kk] -> w2t[kk][c][oc] ----------------
__global__ void k_transpose_w(const float* __restrict__ w, float* __restrict__ w2t) {
    int idx = blockIdx.x * 256 + threadIdx.x;       // 589824 = 9*256*256
    int oc = idx & 255;
    int c  = (idx >> 8) & 255;
    int kk = idx >> 16;
    w2t[idx] = w[(oc * 256 + c) * 9 + kk];
}

// ---------------- K1: offset conv partials ----------------
// grid (64, 8): blockIdx.x = pixel tile of 256, blockIdx.y = c-chunk of 32
// part[chunk][oc(27)][p(16384)]
__global__ void k_offconv(const float* __restrict__ x, const float* __restrict__ w_off,
                          float* __restrict__ part) {
    int p  = blockIdx.x * 256 + threadIdx.x;        // 0..16383
    int b  = p >> 12;
    int hw = p & 4095;
    int h  = hw >> 6;
    int w  = hw & 63;
    int c0 = blockIdx.y * 32;

    float acc[27];
#pragma unroll
    for (int o = 0; o < 27; ++o) acc[o] = 0.f;

    const float* xb = x + (b * C_ + c0) * HW_;
    for (int c = 0; c < 32; ++c) {
        const float* xc = xb + c * HW_;
        const float* wc = w_off + (c0 + c) * 9;     // + o*2304 gives w_off[o][c0+c][t]
        float v[9];
#pragma unroll
        for (int t = 0; t < 9; ++t) {
            int ki = t / 3, kj = t % 3;
            int yy = h + ki - 1, xx = w + kj - 1;
            bool ok = (yy >= 0) & (yy < H_) & (xx >= 0) & (xx < W_);
            v[t] = ok ? xc[yy * W_ + xx] : 0.f;
        }
#pragma unroll
        for (int o = 0; o < 27; ++o) {
            const float* wo = wc + o * 2304;
#pragma unroll
            for (int t = 0; t < 9; ++t) acc[o] += v[t] * wo[t];
        }
    }
    float* pp = part + blockIdx.y * (27 * NPX_) + p;
#pragma unroll
    for (int o = 0; o < 27; ++o) pp[o * NPX_] = acc[o];
}

// ---------------- K1b: reduce partials + bias -> off[ch(27)][p(16384)] ----------------
__global__ void k_offreduce(const float* __restrict__ part, const float* __restrict__ b_off,
                            float* __restrict__ off) {
    int idx = blockIdx.x * 256 + threadIdx.x;       // 442368
    int oc  = idx >> 14;
    float s = b_off[oc];
#pragma unroll
    for (int j = 0; j < 8; ++j) s += part[j * (27 * NPX_) + idx];
    off[idx] = s;
}

// ---------------- K2: bilinear sample + implicit GEMM ----------------
// grid (256, 4): blockIdx.x = pixel tile of 64 (one (b,h) row), blockIdx.y = oc tile of 64
// out[(b*256+oc)*4096 + hw] = sum_{c,kk} val * w + bias   (y, pre-GN)
__global__ void k_dcn_gemm(const float* __restrict__ x, const float* __restrict__ off,
                           const float* __restrict__ w2t, const float* __restrict__ bias,
                           float* __restrict__ out) {
    __shared__ float vs[16][64];

    int tid  = threadIdx.x;
    int px0  = blockIdx.x * 64;                     // one full row (b,h)
    int b    = px0 >> 12;
    int hw0  = px0 & 4095;
    int h    = hw0 >> 6;
    int oc0  = blockIdx.y * 64;

    int s_px = tid & 63;                            // staging pixel lane
    int wv   = tid >> 6;                            // wave id 0..3

    int a_oc = (tid & 15) * 4;                      // accum oc offset 0..60
    int a_px = (tid >> 4) * 4;                      // accum px offset 0..60

    float acc[4][4];
#pragma unroll
    for (int i = 0; i < 4; ++i)
#pragma unroll
        for (int j = 0; j < 4; ++j) acc[i][j] = 0.f;

    const float* xb = x + b * (C_ * HW_);
    int p_glob = px0 + s_px;

    for (int kk = 0; kk < 9; ++kk) {
        int ki = kk / 3, kj = kk % 3;
        float dy = off[(2 * kk) * NPX_ + p_glob];
        float dx = off[(2 * kk + 1) * NPX_ + p_glob];
        float mk = off[(18 + kk) * NPX_ + p_glob];
        mk = 1.f / (1.f + __expf(-mk));

        float py  = (float)(h + ki - 1) + dy;
        float pxf = (float)(s_px + kj - 1) + dx;
        float y0f = floorf(py), x0f = floorf(pxf);
        float ly = py - y0f, lx = pxf - x0f;
        int y0 = (int)y0f, x0 = (int)x0f;
        int y1 = y0 + 1, x1 = x0 + 1;

        float w00 = (1.f - ly) * (1.f - lx) * mk;
        float w01 = (1.f - ly) * lx * mk;
        float w10 = ly * (1.f - lx) * mk;
        float w11 = ly * lx * mk;
        bool vy0 = (y0 >= 0) & (y0 < H_);
        bool vy1 = (y1 >= 0) & (y1 < H_);
        bool vx0 = (x0 >= 0) & (x0 < W_);
        bool vx1 = (x1 >= 0) & (x1 < W_);
        if (!(vy0 & vx0)) w00 = 0.f;
        if (!(vy0 & vx1)) w01 = 0.f;
        if (!(vy1 & vx0)) w10 = 0.f;
        if (!(vy1 & vx1)) w11 = 0.f;
        int cy0 = min(max(y0, 0), H_ - 1), cy1 = min(max(y1, 0), H_ - 1);
        int cx0 = min(max(x0, 0), W_ - 1), cx1 = min(max(x1, 0), W_ - 1);
        int o00 = cy0 * W_ + cx0, o01 = cy0 * W_ + cx1;
        int o10 = cy1 * W_ + cx0, o11 = cy1 * W_ + cx1;

        for (int ch = 0; ch < 16; ++ch) {           // 16 chunks of 16 channels
            __syncthreads();
            // stage val[c_local][px] for c_local = wv*4 + j
#pragma unroll
            for (int j = 0; j < 4; ++j) {
                int cl = wv * 4 + j;
                const float* xc = xb + (ch * 16 + cl) * HW_;
                float g = w00 * xc[o00] + w01 * xc[o01] + w10 * xc[o10] + w11 * xc[o11];
                vs[cl][s_px] = g;
            }
            __syncthreads();

            const float* wrow = w2t + kk * 65536 + (ch * 16) * 256 + oc0 + a_oc;
#pragma unroll
            for (int c = 0; c < 16; ++c) {
                float4 w4 = *reinterpret_cast<const float4*>(wrow + c * 256);
                float4 v4 = *reinterpret_cast<const float4*>(&vs[c][a_px]);
                acc[0][0] += w4.x * v4.x; acc[0][1] += w4.x * v4.y;
                acc[0][2] += w4.x * v4.z; acc[0][3] += w4.x * v4.w;
                acc[1][0] += w4.y * v4.x; acc[1][1] += w4.y * v4.y;
                acc[1][2] += w4.y * v4.z; acc[1][3] += w4.y * v4.w;
                acc[2][0] += w4.z * v4.x; acc[2][1] += w4.z * v4.y;
                acc[2][2] += w4.z * v4.z; acc[2][3] += w4.z * v4.w;
                acc[3][0] += w4.w * v4.x; acc[3][1] += w4.w * v4.y;
                acc[3][2] += w4.w * v4.z; acc[3][3] += w4.w * v4.w;
            }
        }
    }

#pragma unroll
    for (int i = 0; i < 4; ++i) {
        int oc = oc0 + a_oc + i;
        float bv = bias[oc];
        float4 r;
        r.x = acc[i][0] + bv; r.y = acc[i][1] + bv;
        r.z = acc[i][2] + bv; r.w = acc[i][3] + bv;
        *reinterpret_cast<float4*>(out + (b * CO_ + oc) * HW_ + hw0 + a_px) = r;
    }
}

// ---------------- K3: GN partial sums ----------------
// grid 1024 = b*256 + i, each block reduces 4096 contiguous elements
__global__ void k_gn_partial(const float* __restrict__ y, float* __restrict__ part) {
    int base = blockIdx.x * 4096;
    const float4* p = reinterpret_cast<const float4*>(y + base);
    float s = 0.f, sq = 0.f;
    for (int j = threadIdx.x; j < 1024; j += 256) {
        float4 v = p[j];
        s  += v.x + v.y + v.z + v.w;
        sq += v.x * v.x + v.y * v.y + v.z * v.z + v.w * v.w;
    }
#pragma unroll
    for (int o = 32; o > 0; o >>= 1) {
        s  += __shfl_down(s, o, 64);
        sq += __shfl_down(sq, o, 64);
    }
    __shared__ float red[8];
    int wv = threadIdx.x >> 6;
    if ((threadIdx.x & 63) == 0) { red[wv * 2] = s; red[wv * 2 + 1] = sq; }
    __syncthreads();
    if (threadIdx.x == 0) {
        float S = 0.f, SQ = 0.f;
#pragma unroll
        for (int k = 0; k < 4; ++k) { S += red[k * 2]; SQ += red[k * 2 + 1]; }
        part[blockIdx.x * 2] = S;
        part[blockIdx.x * 2 + 1] = SQ;
    }
}

// ---------------- K4: finalize stats ----------------
// grid 4 (batch), 256 threads
__global__ void k_gn_stats(const float* __restrict__ part, float* __restrict__ stats) {
    int b = blockIdx.x;
    const float2* pp = reinterpret_cast<const float2*>(part);
    float2 v = pp[b * 256 + threadIdx.x];
    float s = v.x, sq = v.y;
#pragma unroll
    for (int o = 32; o > 0; o >>= 1) {
        s  += __shfl_down(s, o, 64);
        sq += __shfl_down(sq, o, 64);
    }
    __shared__ float red[8];
    int wv = threadIdx.x >> 6;
    if ((threadIdx.x & 63) == 0) { red[wv * 2] = s; red[wv * 2 + 1] = sq; }
    __syncthreads();
    if (threadIdx.x == 0) {
        float S = 0.f, SQ = 0.f;
#pragma unroll
        for (int k = 0; k < 4; ++k) { S += red[k * 2]; SQ += red[k * 2 + 1]; }
        const float n = (float)(CO_ * HW_);        // 1048576 per batch
        float mean = S / n;
        float var  = SQ / n - mean * mean;
        stats[b * 2] = mean;
        stats[b * 2 + 1] = rsqrtf(var + GN_EPS_);
    }
}

// ---------------- K5: normalize + affine + relu, in place ----------------
// grid 4096, over 1048576 float4 groups
__global__ void k_gn_apply(float* __restrict__ y, const float* __restrict__ stats,
                           const float* __restrict__ gamma, const float* __restrict__ beta) {
    int e4 = blockIdx.x * 256 + threadIdx.x;        // float4 index
    int b  = e4 >> 18;                              // 262144 float4 per batch
    int oc = (e4 >> 10) & 255;                      // 1024 float4 per channel
    float mean = stats[b * 2], rstd = stats[b * 2 + 1];
    float g  = gamma[oc] * rstd;
    float bb = beta[oc] - mean * g;
    float4* p = reinterpret_cast<float4*>(y);
    float4 v = p[e4];
    v.x = fmaxf(v.x * g + bb, 0.f);
    v.y = fmaxf(v.y * g + bb, 0.f);
    v.z = fmaxf(v.z * g + bb, 0.f);
    v.w = fmaxf(v.w * g + bb, 0.f);
    p[e4] = v;
}

extern "C" void kernel_launch(void* const* d_in, const int* in_sizes, int n_in,
                              void* d_out, int out_size, void* d_ws, size_t ws_size,
                              hipStream_t stream) {
    const float* x     = (const float*)d_in[0];
    const float* w_off = (const float*)d_in[1];
    const float* b_off = (const float*)d_in[2];
    const float* w     = (const float*)d_in[3];
    const float* bias  = (const float*)d_in[4];
    const float* gamma = (const float*)d_in[5];
    const float* beta  = (const float*)d_in[6];
    float* out = (float*)d_out;

    float* W = (float*)d_ws;
    float* part1  = W;                               // 8*27*16384 = 3,538,944 floats
    float* off    = part1 + 8 * 27 * NPX_;           // 27*16384  =   442,368 floats
    float* w2t    = off + 27 * NPX_;                 // 9*256*256 =   589,824 floats
    float* gnpart = w2t + 9 * 256 * 256;             // 2048 floats
    float* stats  = gnpart + 2048;                   // 8 floats

    k_transpose_w<<<2304, 256, 0, stream>>>(w, w2t);
    k_offconv<<<dim3(64, 8), 256, 0, stream>>>(x, w_off, part1);
    k_offreduce<<<1728, 256, 0, stream>>>(part1, b_off, off);
    k_dcn_gemm<<<dim3(256, 4), 256, 0, stream>>>(x, off, w2t, bias, out);
    k_gn_partial<<<1024, 256, 0, stream>>>(out, gnpart);
    k_gn_stats<<<4, 256, 0, stream>>>(gnpart, stats);
    k_gn_apply<<<4096, 256, 0, stream>>>(out, stats, gamma, beta);
}

// Round 3
// 323.517 us; speedup vs baseline: 2.5883x; 2.5883x over previous
//
#include <hip/hip_runtime.h>

#define B_ 4
#define C_ 256
#define H_ 64
#define W_ 64
#define HW_ 4096
#define CO_ 256
#define NPX_ 16384
#define GN_EPS_ 1e-5f

typedef float f32x4 __attribute__((ext_vector_type(4)));
typedef short s16x8 __attribute__((ext_vector_type(8)));

__device__ __forceinline__ short f2bf(float f) {
    union { float f; unsigned u; } v; v.f = f;
    unsigned r = (v.u + 0x7FFFu + ((v.u >> 16) & 1u)) >> 16;
    return (short)(r & 0xFFFFu);
}

// ---------------- K0: w[oc][c][kk] -> wT[kk][oc][c] in bf16 ----------------
// grid 256 (oc), 256 threads (c)
__global__ void k_prep_w(const float* __restrict__ w, short* __restrict__ wT) {
    int oc = blockIdx.x, c = threadIdx.x;
    const float* src = w + (oc * 256 + c) * 9;
    float v[9];
#pragma unroll
    for (int t = 0; t < 9; ++t) v[t] = src[t];
#pragma unroll
    for (int t = 0; t < 9; ++t) wT[(t * 256 + oc) * 256 + c] = f2bf(v[t]);
}

// ---------------- K1: offset conv partials (unchanged, proven) ----------------
__global__ void k_offconv(const float* __restrict__ x, const float* __restrict__ w_off,
                          float* __restrict__ part) {
    int p  = blockIdx.x * 256 + threadIdx.x;
    int b  = p >> 12;
    int hw = p & 4095;
    int h  = hw >> 6;
    int w  = hw & 63;
    int c0 = blockIdx.y * 32;

    float acc[27];
#pragma unroll
    for (int o = 0; o < 27; ++o) acc[o] = 0.f;

    const float* xb = x + (b * C_ + c0) * HW_;
    for (int c = 0; c < 32; ++c) {
        const float* xc = xb + c * HW_;
        const float* wc = w_off + (c0 + c) * 9;
        float v[9];
#pragma unroll
        for (int t = 0; t < 9; ++t) {
            int ki = t / 3, kj = t % 3;
            int yy = h + ki - 1, xx = w + kj - 1;
            bool ok = (yy >= 0) & (yy < H_) & (xx >= 0) & (xx < W_);
            v[t] = ok ? xc[yy * W_ + xx] : 0.f;
        }
#pragma unroll
        for (int o = 0; o < 27; ++o) {
            const float* wo = wc + o * 2304;
#pragma unroll
            for (int t = 0; t < 9; ++t) acc[o] += v[t] * wo[t];
        }
    }
    float* pp = part + blockIdx.y * (27 * NPX_) + p;
#pragma unroll
    for (int o = 0; o < 27; ++o) pp[o * NPX_] = acc[o];
}

// ---------------- K1b: reduce partials + bias ----------------
__global__ void k_offreduce(const float* __restrict__ part, const float* __restrict__ b_off,
                            float* __restrict__ off) {
    int idx = blockIdx.x * 256 + threadIdx.x;
    int oc  = idx >> 14;
    float s = b_off[oc];
#pragma unroll
    for (int j = 0; j < 8; ++j) s += part[j * (27 * NPX_) + idx];
    off[idx] = s;
}

// ---------------- K2: bilinear sample + MFMA implicit GEMM ----------------
// grid 256: blockIdx.x -> 64-px tile (one (b,h) row). 512 threads = 8 waves.
// Wave w: oc slab (w&3)*64, px half (w>>2)*32. All 256 oc handled in-block.
// A = val_lds[px][c] bf16 (XOR-swizzled), B = wT[kk][oc][c] bf16 from global (L2).
__global__ __launch_bounds__(512, 2) void k_dcn_mfma(
        const float* __restrict__ x, const float* __restrict__ off,
        const short* __restrict__ wT, const float* __restrict__ bias,
        float* __restrict__ out, float* __restrict__ gnpart) {
    __shared__ char vs[32768];          // val tile: 64 px * 256 c * 2B, swizzled
    __shared__ float red[16];

    int tid  = threadIdx.x;
    int lane = tid & 63;
    int wv   = tid >> 6;                // wave 0..7

    int px0  = blockIdx.x * 64;
    int b    = px0 >> 12;
    int hw0  = px0 & 4095;
    int h    = hw0 >> 6;

    // sampling role: px = lane, c chunk = wv*32
    int c0s = wv * 32;
    const float* xb = x + b * (C_ * HW_);
    int p_glob = px0 + lane;

    // mfma role
    int oc0 = (wv & 3) * 64;
    int pxh = (wv >> 2) * 32;

    f32x4 acc[2][4];
#pragma unroll
    for (int i = 0; i < 2; ++i)
#pragma unroll
        for (int j = 0; j < 4; ++j) acc[i][j] = (f32x4)0.f;

    for (int kk = 0; kk < 9; ++kk) {
        int ki = kk / 3, kj = kk % 3;

        __syncthreads();                // previous MFMA reads done

        // ---- sampling phase: this thread fills val[px=lane][c0s..c0s+31] ----
        float dy = off[(2 * kk) * NPX_ + p_glob];
        float dx = off[(2 * kk + 1) * NPX_ + p_glob];
        float mk = off[(18 + kk) * NPX_ + p_glob];
        mk = 1.f / (1.f + __expf(-mk));

        float py  = (float)(h + ki - 1) + dy;
        float pxf = (float)(lane + kj - 1) + dx;
        float y0f = floorf(py), x0f = floorf(pxf);
        float ly = py - y0f, lx = pxf - x0f;
        int y0 = (int)y0f, x0 = (int)x0f;
        int y1 = y0 + 1, x1 = x0 + 1;

        float w00 = (1.f - ly) * (1.f - lx) * mk;
        float w01 = (1.f - ly) * lx * mk;
        float w10 = ly * (1.f - lx) * mk;
        float w11 = ly * lx * mk;
        bool vy0 = (y0 >= 0) & (y0 < H_);
        bool vy1 = (y1 >= 0) & (y1 < H_);
        bool vx0 = (x0 >= 0) & (x0 < W_);
        bool vx1 = (x1 >= 0) & (x1 < W_);
        if (!(vy0 & vx0)) w00 = 0.f;
        if (!(vy0 & vx1)) w01 = 0.f;
        if (!(vy1 & vx0)) w10 = 0.f;
        if (!(vy1 & vx1)) w11 = 0.f;
        int cy0 = min(max(y0, 0), H_ - 1), cy1 = min(max(y1, 0), H_ - 1);
        int cx0 = min(max(x0, 0), W_ - 1), cx1 = min(max(x1, 0), W_ - 1);
        int o00 = cy0 * W_ + cx0, o01 = cy0 * W_ + cx1;
        int o10 = cy1 * W_ + cx0, o11 = cy1 * W_ + cx1;

        int swz = (lane & 7) << 4;
        s16x8 pk;
#pragma unroll
        for (int cc = 0; cc < 32; ++cc) {
            const float* xc = xb + (c0s + cc) * HW_;
            float g = w00 * xc[o00] + w01 * xc[o01] + w10 * xc[o10] + w11 * xc[o11];
            pk[cc & 7] = f2bf(g);
            if ((cc & 7) == 7) {
                int byte = (lane * 512 + (c0s + (cc & ~7)) * 2) ^ swz;
                *reinterpret_cast<s16x8*>(&vs[byte]) = pk;
            }
        }
        __syncthreads();

        // ---- MFMA phase: 8 K-steps of 32 over c ----
        const short* wkk = wT + kk * 65536;
#pragma unroll
        for (int ks = 0; ks < 8; ++ks) {
            int k0 = ks * 32;
            int cA = k0 + (lane >> 4) * 8;
            s16x8 a[2];
#pragma unroll
            for (int mt = 0; mt < 2; ++mt) {
                int px = pxh + mt * 16 + (lane & 15);
                int byte = (px * 512 + cA * 2) ^ ((px & 7) << 4);
                a[mt] = *reinterpret_cast<const s16x8*>(&vs[byte]);
            }
            s16x8 bfr[4];
#pragma unroll
            for (int nt = 0; nt < 4; ++nt) {
                int oc = oc0 + nt * 16 + (lane & 15);
                bfr[nt] = *reinterpret_cast<const s16x8*>(wkk + oc * 256 + cA);
            }
#pragma unroll
            for (int mt = 0; mt < 2; ++mt)
#pragma unroll
                for (int nt = 0; nt < 4; ++nt)
                    acc[mt][nt] = __builtin_amdgcn_mfma_f32_16x16x32_bf16(
                        a[mt], bfr[nt], acc[mt][nt], 0, 0, 0);
        }
    }

    // ---- epilogue: bias, store, fused GN partial ----
    float s = 0.f, sq = 0.f;
#pragma unroll
    for (int nt = 0; nt < 4; ++nt) {
        int oc = oc0 + nt * 16 + (lane & 15);
        float bv = bias[oc];
        float* orow = out + (b * CO_ + oc) * HW_ + hw0 + pxh;
#pragma unroll
        for (int mt = 0; mt < 2; ++mt) {
            f32x4 r = acc[mt][nt];
            r.x += bv; r.y += bv; r.z += bv; r.w += bv;
            s  += r.x + r.y + r.z + r.w;
            sq += r.x * r.x + r.y * r.y + r.z * r.z + r.w * r.w;
            *reinterpret_cast<f32x4*>(orow + mt * 16 + (lane >> 4) * 4) = r;
        }
    }
#pragma unroll
    for (int o = 32; o > 0; o >>= 1) {
        s  += __shfl_down(s, o, 64);
        sq += __shfl_down(sq, o, 64);
    }
    if (lane == 0) { red[wv * 2] = s; red[wv * 2 + 1] = sq; }
    __syncthreads();
    if (tid == 0) {
        float S = 0.f, SQ = 0.f;
#pragma unroll
        for (int k = 0; k < 8; ++k) { S += red[k * 2]; SQ += red[k * 2 + 1]; }
        gnpart[blockIdx.x * 2]     = S;
        gnpart[blockIdx.x * 2 + 1] = SQ;
    }
}

// ---------------- K4: finalize stats. grid 4 (batch), 64 threads ----------------
__global__ void k_gn_stats(const float* __restrict__ part, float* __restrict__ stats) {
    int b = blockIdx.x;
    float2 v = reinterpret_cast<const float2*>(part)[b * 64 + threadIdx.x];
    float s = v.x, sq = v.y;
#pragma unroll
    for (int o = 32; o > 0; o >>= 1) {
        s  += __shfl_down(s, o, 64);
        sq += __shfl_down(sq, o, 64);
    }
    if (threadIdx.x == 0) {
        const float n = (float)(CO_ * HW_);
        float mean = s / n;
        float var  = sq / n - mean * mean;
        stats[b * 2] = mean;
        stats[b * 2 + 1] = rsqrtf(var + GN_EPS_);
    }
}

// ---------------- K5: normalize + affine + relu ----------------
__global__ void k_gn_apply(float* __restrict__ y, const float* __restrict__ stats,
                           const float* __restrict__ gamma, const float* __restrict__ beta) {
    int e4 = blockIdx.x * 256 + threadIdx.x;
    int b  = e4 >> 18;
    int oc = (e4 >> 10) & 255;
    float mean = stats[b * 2], rstd = stats[b * 2 + 1];
    float g  = gamma[oc] * rstd;
    float bb = beta[oc] - mean * g;
    float4* p = reinterpret_cast<float4*>(y);
    float4 v = p[e4];
    v.x = fmaxf(v.x * g + bb, 0.f);
    v.y = fmaxf(v.y * g + bb, 0.f);
    v.z = fmaxf(v.z * g + bb, 0.f);
    v.w = fmaxf(v.w * g + bb, 0.f);
    p[e4] = v;
}

extern "C" void kernel_launch(void* const* d_in, const int* in_sizes, int n_in,
                              void* d_out, int out_size, void* d_ws, size_t ws_size,
                              hipStream_t stream) {
    const float* x     = (const float*)d_in[0];
    const float* w_off = (const float*)d_in[1];
    const float* b_off = (const float*)d_in[2];
    const float* w     = (const float*)d_in[3];
    const float* bias  = (const float*)d_in[4];
    const float* gamma = (const float*)d_in[5];
    const float* beta  = (const float*)d_in[6];
    float* out = (float*)d_out;

    float* Wp = (float*)d_ws;
    float* part1  = Wp;                              // 8*27*16384 floats
    float* off    = part1 + 8 * 27 * NPX_;           // 27*16384 floats
    short* wT     = (short*)(off + 27 * NPX_);       // 9*256*256 bf16
    float* gnpart = off + 27 * NPX_ + (9 * 256 * 256) / 2;  // 512 floats
    float* stats  = gnpart + 512;                    // 8 floats

    k_prep_w<<<256, 256, 0, stream>>>(w, wT);
    k_offconv<<<dim3(64, 8), 256, 0, stream>>>(x, w_off, part1);
    k_offreduce<<<1728, 256, 0, stream>>>(part1, b_off, off);
    k_dcn_mfma<<<256, 512, 0, stream>>>(x, off, wT, bias, out, gnpart);
    k_gn_stats<<<4, 64, 0, stream>>>(gnpart, stats);
    k_gn_apply<<<4096, 256, 0, stream>>>(out, stats, gamma, beta);
}